// Round 15
// baseline (198.446 us; speedup 1.0000x reference)
//
#include <hip/hip_runtime.h>
#include <hip/hip_bf16.h>
#include <math.h>

// LoRA attention, MI355X bf16-MFMA pipeline, round 15.
// r14 with ONE change in k_gm: A triple-buffered / B double-buffered LDS
// (80 KiB, still 2 blocks/CU) -> A prefetch lead grows 1 phase -> 3 phases
// (~1350 cyc > HBM ~900), B 2 phases. One vmcnt(4) per K-step retires exactly
// tile s+1. Fixes the per-step vmcnt stall that capped HBM-fed GEMMs at ~670
// TF while L2-fed proj ran 1036 TF.

typedef __attribute__((ext_vector_type(4))) float f32x4;
typedef __attribute__((ext_vector_type(8))) short bf8;   // 8 x bf16
typedef __attribute__((ext_vector_type(4))) short bf4;   // 4 x bf16

__device__ __forceinline__ unsigned short f2bf(float f) {
  union { float f; unsigned u; } c; c.f = f;
  return (unsigned short)((c.u + 0x7fffu + ((c.u >> 16) & 1u)) >> 16);
}
__device__ __forceinline__ void gload16(const void* g, void* l) {
  __builtin_amdgcn_global_load_lds((const __attribute__((address_space(1))) void*)g,
                                   (__attribute__((address_space(3))) void*)l, 16, 0, 0);
}

// ---------------- head: cast fp32->bf16 | Weff fold | bias concat | lsum zero ----------------
__global__ __launch_bounds__(256)
void k_head(const float* __restrict__ x, __hip_bfloat16* __restrict__ Xb,
            const float* __restrict__ W0, const float* __restrict__ A0, const float* __restrict__ B0,
            const float* __restrict__ W1, const float* __restrict__ A1, const float* __restrict__ B1,
            const float* __restrict__ W2, const float* __restrict__ A2, const float* __restrict__ B2,
            const float* __restrict__ bq, const float* __restrict__ bk, const float* __restrict__ bv,
            __hip_bfloat16* __restrict__ WeA, float* __restrict__ bcat, float* __restrict__ lsum) {
  const int b = blockIdx.x;
  if (b < 3072) {                       // ---- cast: 8192x768 fp32 -> bf16, 8/thread ----
    long i = ((long)b * 256 + threadIdx.x) * 8;
    float4 a = *(const float4*)&x[i];
    float4 c = *(const float4*)&x[i + 4];
    union { bf8 v; unsigned short h[8]; } u;
    u.h[0] = f2bf(a.x); u.h[1] = f2bf(a.y); u.h[2] = f2bf(a.z); u.h[3] = f2bf(a.w);
    u.h[4] = f2bf(c.x); u.h[5] = f2bf(c.y); u.h[6] = f2bf(c.z); u.h[7] = f2bf(c.w);
    *(bf8*)&Xb[i] = u.v;
  } else {                              // ---- fold: Weff = W + B@A, concat [2304][768] ----
    int idx = (b - 3072) * 256 + threadIdx.x;
    if (idx < 2304)
      bcat[idx] = (idx < 768) ? bq[idx] : (idx < 1536) ? bk[idx - 768] : bv[idx - 1536];
    if (idx < 8192) lsum[idx] = 0.0f;
    int t = idx / 589824, j = idx - t * 589824;
    const float* W = (t == 0) ? W0 : (t == 1) ? W1 : W2;
    const float* A = (t == 0) ? A0 : (t == 1) ? A1 : A2;
    const float* Bl = (t == 0) ? B0 : (t == 1) ? B1 : B2;
    int d = j % 768, o = j / 768;
    float acc = W[j];
    #pragma unroll
    for (int r = 0; r < 32; ++r) acc += Bl[o * 32 + r] * A[r * 768 + d];
    WeA[idx] = __float2bfloat16(acc);
  }
}

// ---------------- 128x128x64 8-wave N-marching GEMM, A-3buf/B-2buf ----------------
// Out[m][n] = sum_k A[m][k] * B[n][k]
// MODE 0: PV   (A=P' ld4096, B=Vt ld8192 +z*4096, fp32 out / lsum)       MARCH=1
// MODE 1: scores (A=Q ld1536, B=A+768; P'=exp2(acc*scale2) + atomic lsum) MARCH=4
// MODE 3: proj (col<1536 -> bf16 [8192][1536] +bias; else Vt +bias)       MARCH=3
// LDS: A bufs 0/16K/32K (tile t -> buf t%3), B bufs 48K/64K (t -> t%2).
// Per step s: Ph0 reads A[s%3] mh0 + B[s&1], stages A(s+2);
//             Ph1 reads A[s%3] mh1, stages B(s+2); vmcnt(4) retires tile s+1.
template<int MODE, int MARCH>
__global__ __launch_bounds__(512, 4)
void k_gm(const __hip_bfloat16* __restrict__ Ag, const __hip_bfloat16* __restrict__ Bg,
          const float* __restrict__ bias, void* __restrict__ Og, void* __restrict__ Og2,
          float* __restrict__ lsum, float scale)
{
  __shared__ short lds[40960];   // 80 KiB: A[3][64r,64k x2half] + B[2][...]
  constexpr int NT = (MODE == 0) ? 64 : 12;
  constexpr int S = NT * MARCH;
  const int tid = threadIdx.x, w = tid >> 6, lane = tid & 63;
  const int wm = w >> 2, wn = w & 3;
  const int lnlo = lane & 15, lnhi = lane >> 4;

  // T1 XCD swizzle, N-fast tile mapping
  const int gy = gridDim.y;
  const int nwg = gridDim.x * gy;
  const int w0 = blockIdx.y * gridDim.x + blockIdx.x;
  const int wid = (w0 & 7) * (nwg >> 3) + (w0 >> 3);
  const long M0 = (long)(wid / gy) * 128;
  const long NG0 = (long)(wid % gy) * (128 * MARCH);

  const __hip_bfloat16 *A, *B; long lda, ldb;
  if constexpr (MODE == 0) {
    A = Ag + (long)blockIdx.z * 4096 * 4096; lda = 4096;
    B = Bg + (long)blockIdx.z * 4096;        ldb = 8192;
  } else if constexpr (MODE == 1) {
    A = Ag + (long)blockIdx.z * 4096 * 1536; B = A + 768; lda = 1536; ldb = 1536;
  } else {
    A = Ag; B = Bg; lda = 768; ldb = 768;
  }

  // staging: half-tile 64 rows x 64 k = 1 gload16/thread; T2 pre-swizzled source col
  const int srow = tid >> 3;                       // 0..63
  const int scol = (((tid & 7) ^ (srow & 7)) << 3);
  const __hip_bfloat16* pA[2] = { A + (M0 + srow) * lda + scol, A + (M0 + 64 + srow) * lda + scol };
  const __hip_bfloat16* pB[2] = { B + (NG0 + srow) * ldb + scol, B + (NG0 + 64 + srow) * ldb + scol };
  char* Lc = (char*)lds;
  const int wbyte = w * 1024;
  auto stage = [&](int op, int h, int t) {         // 1 gload16/thread
    const int tc = (t < S) ? t : S - 1;            // clamped source (tail: dst never read)
    const int bu = (op == 0) ? (t % 3) : (t & 1);
    char* dst = Lc + (op == 0 ? bu * 16384 : 49152 + bu * 16384) + h * 8192 + wbyte;
    long off;
    if (op == 0) off = (long)(tc % NT) * 64;
    else         off = (long)(tc / NT) * 128 * ldb + (long)(tc % NT) * 64;
    gload16((op ? pB[h] : pA[h]) + off, dst);
  };
  auto rdA = [&](int row, int k, int bu) -> bf8 {  // T2-swizzled LDS read
    const int sb = ((k << 6) + (lnhi << 4)) ^ ((row & 7) << 4);
    return *(const bf8*)(Lc + bu * 16384 + row * 128 + sb);
  };
  auto rdB = [&](int row, int k, int bu) -> bf8 {
    const int sb = ((k << 6) + (lnhi << 4)) ^ ((row & 7) << 4);
    return *(const bf8*)(Lc + 49152 + bu * 16384 + row * 128 + sb);
  };

  f32x4 acc[4][2] = {};   // wave tile 64x32: [m-frag][n-frag]

  // per-n-tile epilogue (no LDS use -> overlaps with in-flight staging)
  auto dump = [&](int j) {
    #pragma unroll
    for (int mi = 0; mi < 4; ++mi) {
      const long row = M0 + wm * 64 + mi * 16 + lnhi * 4;
      if constexpr (MODE == 0) {
        float* Of = (float*)Og + (long)blockIdx.z * 4096 * 768;
        const float* lz = lsum + (long)blockIdx.z * 4096;
        float linv[4];
        #pragma unroll
        for (int r = 0; r < 4; ++r) linv[r] = 1.0f / lz[row + r];
        #pragma unroll
        for (int ni = 0; ni < 2; ++ni) {
          const long col = NG0 + wn * 32 + ni * 16 + lnlo;
          #pragma unroll
          for (int r = 0; r < 4; ++r) Of[(row + r) * 768 + col] = acc[mi][ni][r] * linv[r];
        }
      } else if constexpr (MODE == 1) {
        __hip_bfloat16* Ob = (__hip_bfloat16*)Og + (long)blockIdx.z * 4096 * 4096;
        float* lz = lsum + (long)blockIdx.z * 4096;
        float rs[4] = {0.f, 0.f, 0.f, 0.f};
        #pragma unroll
        for (int ni = 0; ni < 2; ++ni) {
          const long col = NG0 + (long)j * 128 + wn * 32 + ni * 16 + lnlo;
          #pragma unroll
          for (int r = 0; r < 4; ++r) {
            const float e = exp2f(fminf(acc[mi][ni][r] * scale, 101.0f));  // log2e folded in scale
            rs[r] += e;
            *(unsigned short*)&Ob[(row + r) * 4096 + col] = f2bf(e);
          }
        }
        #pragma unroll
        for (int r = 0; r < 4; ++r) {
          float v = rs[r];
          v += __shfl_xor(v, 1); v += __shfl_xor(v, 2);
          v += __shfl_xor(v, 4); v += __shfl_xor(v, 8);
          if (lnlo == 0) atomicAdd(&lz[row + r], v);
        }
      } else {
        #pragma unroll
        for (int ni = 0; ni < 2; ++ni) {
          const long col = NG0 + (long)j * 128 + wn * 32 + ni * 16 + lnlo;
          const float bvl = bias[col];
          if (col < 1536) {
            __hip_bfloat16* O = (__hip_bfloat16*)Og;
            #pragma unroll
            for (int r = 0; r < 4; ++r)
              *(unsigned short*)&O[(row + r) * 1536 + col] = f2bf(acc[mi][ni][r] + bvl);
          } else {
            __hip_bfloat16* O2 = (__hip_bfloat16*)Og2;
            bf4 v;
            #pragma unroll
            for (int r = 0; r < 4; ++r) v[r] = (short)f2bf(acc[mi][ni][r] + bvl);
            *(bf4*)&O2[(col - 1536) * 8192 + row] = v;
          }
        }
      }
    }
    #pragma unroll
    for (int mi = 0; mi < 4; ++mi)
      #pragma unroll
      for (int ni = 0; ni < 2; ++ni) acc[mi][ni] = (f32x4){0.f, 0.f, 0.f, 0.f};
  };

  // prologue: A(0),B(0),A(1),B(1); vmcnt(4) retires A(0),B(0)
  stage(0,0,0); stage(0,1,0); stage(1,0,0); stage(1,1,0);
  stage(0,0,1); stage(0,1,1); stage(1,0,1); stage(1,1,1);
  asm volatile("s_waitcnt vmcnt(4)" ::: "memory");
  __builtin_amdgcn_s_barrier();
  asm volatile("" ::: "memory");

  bf8 af[2][2], bv[2][2];
  for (int s = 0; s < S; ++s) {
    if (MARCH > 1 && s > 0 && (s % NT) == 0) dump(s / NT - 1);
    const int ab = s % 3, bb = s & 1;

    // ---- Ph0 (m-half 0): read af(mh0)+bv; stage A(s+2) -> buf (s+2)%3 ----
    #pragma unroll
    for (int m = 0; m < 2; ++m)
      #pragma unroll
      for (int k = 0; k < 2; ++k) af[m][k] = rdA(wm * 64 + m * 16 + lnlo, k, ab);
    #pragma unroll
    for (int n = 0; n < 2; ++n)
      #pragma unroll
      for (int k = 0; k < 2; ++k) bv[n][k] = rdB(wn * 32 + n * 16 + lnlo, k, bb);
    stage(0,0,s+2); stage(0,1,s+2);
    asm volatile("" ::: "memory");
    __builtin_amdgcn_s_barrier();
    __builtin_amdgcn_s_setprio(1);
    #pragma unroll
    for (int m = 0; m < 2; ++m)
      #pragma unroll
      for (int n = 0; n < 2; ++n) {
        acc[m][n] = __builtin_amdgcn_mfma_f32_16x16x32_bf16(af[m][0], bv[n][0], acc[m][n], 0,0,0);
        acc[m][n] = __builtin_amdgcn_mfma_f32_16x16x32_bf16(af[m][1], bv[n][1], acc[m][n], 0,0,0);
      }
    __builtin_amdgcn_s_setprio(0);
    __builtin_amdgcn_s_barrier();
    asm volatile("" ::: "memory");

    // ---- Ph1 (m-half 1): read af(mh1); stage B(s+2) -> buf (s+2)&1 ----
    #pragma unroll
    for (int m = 0; m < 2; ++m)
      #pragma unroll
      for (int k = 0; k < 2; ++k) af[m][k] = rdA(wm * 64 + 32 + m * 16 + lnlo, k, ab);
    stage(1,0,s+2); stage(1,1,s+2);
    asm volatile("" ::: "memory");
    __builtin_amdgcn_s_barrier();
    __builtin_amdgcn_s_setprio(1);
    #pragma unroll
    for (int m = 0; m < 2; ++m)
      #pragma unroll
      for (int n = 0; n < 2; ++n) {
        acc[2+m][n] = __builtin_amdgcn_mfma_f32_16x16x32_bf16(af[m][0], bv[n][0], acc[2+m][n], 0,0,0);
        acc[2+m][n] = __builtin_amdgcn_mfma_f32_16x16x32_bf16(af[m][1], bv[n][1], acc[2+m][n], 0,0,0);
      }
    __builtin_amdgcn_s_setprio(0);
    asm volatile("s_waitcnt vmcnt(4)" ::: "memory");   // A(s+1),B(s+1) landed
    __builtin_amdgcn_s_barrier();
    asm volatile("" ::: "memory");
  }

  dump(MARCH - 1);
}

extern "C" void kernel_launch(void* const* d_in, const int* in_sizes, int n_in,
                              void* d_out, int out_size, void* d_ws, size_t ws_size,
                              hipStream_t stream) {
  const float* x  = (const float*)d_in[0];
  const float* Wq = (const float*)d_in[1]; const float* bq = (const float*)d_in[2];
  const float* Wk = (const float*)d_in[3]; const float* bk = (const float*)d_in[4];
  const float* Wv = (const float*)d_in[5]; const float* bv = (const float*)d_in[6];
  const float* Aq = (const float*)d_in[7]; const float* Bq = (const float*)d_in[8];
  const float* Ak = (const float*)d_in[9]; const float* Bk = (const float*)d_in[10];
  const float* Av = (const float*)d_in[11]; const float* Bv = (const float*)d_in[12];

  // ws layout (bf16 elems), ~121 MB
  __hip_bfloat16* Xb   = (__hip_bfloat16*)d_ws;        // [8192][768]
  __hip_bfloat16* WeA  = Xb  + 6291456;                // [2304][768]
  __hip_bfloat16* QKb  = WeA + 1769472;                // [8192][1536] (Q 0-767, K 768-1535)
  __hip_bfloat16* Vt   = QKb + 12582912;               // [768][8192]
  __hip_bfloat16* Pb   = Vt  + 6291456;                // [2][4096][4096] unnormalized exp
  float*          bcat = (float*)(Pb + 33554432);      // [2304]
  float*          lsum = bcat + 2304;                  // [2][4096] row sums
  float* out = (float*)d_out;

  // head: cast (blocks 0-3071) + fold/bias/lsum-zero (blocks 3072-9983)
  k_head<<<9984, 256, 0, stream>>>(x, Xb, Wq, Aq, Bq, Wk, Ak, Bk, Wv, Av, Bv,
                                   bq, bk, bv, WeA, bcat, lsum);

  // projections: M=8192, N=2304, K=768 (march 3 -> 384 blocks, single round)
  k_gm<3, 3><<<dim3(64, 6, 1), 512, 0, stream>>>(Xb, WeA, bcat, QKb, Vt, nullptr, 1.0f);
  // scores + exp + rowsum: per batch M=N=4096, K=768 (march 4); scale·log2e folded
  const float sc2 = 0.036084391824351615f * 1.4426950408889634f;
  k_gm<1, 4><<<dim3(32, 8, 2), 512, 0, stream>>>(QKb, nullptr, nullptr, Pb, nullptr, lsum, sc2);
  // PV: per batch M=4096, N=768, K=4096 (march 1); epilogue normalizes by lsum
  k_gm<0, 1><<<dim3(32, 6, 2), 512, 0, stream>>>(Pb, Vt, nullptr, out, nullptr, lsum, 1.0f);
}

// Round 16
// 193.338 us; speedup vs baseline: 1.0264x; 1.0264x over previous
//
#include <hip/hip_runtime.h>
#include <hip/hip_bf16.h>
#include <math.h>

// LoRA attention, MI355X bf16-MFMA pipeline, round 16 = round 14 verbatim
// (champion, 191.4 us). r15's deeper-prefetch theory was falsified; reverting.
// Structure: head(cast+fold+bias+lsum) | proj 128^2 march-3 | scores 128^2
// march-4 fused exp2+rowsum | PV 128^2, epilogue normalize. r8 GEMM schedule.

typedef __attribute__((ext_vector_type(4))) float f32x4;
typedef __attribute__((ext_vector_type(8))) short bf8;   // 8 x bf16
typedef __attribute__((ext_vector_type(4))) short bf4;   // 4 x bf16

__device__ __forceinline__ unsigned short f2bf(float f) {
  union { float f; unsigned u; } c; c.f = f;
  return (unsigned short)((c.u + 0x7fffu + ((c.u >> 16) & 1u)) >> 16);
}
__device__ __forceinline__ void gload16(const void* g, void* l) {
  __builtin_amdgcn_global_load_lds((const __attribute__((address_space(1))) void*)g,
                                   (__attribute__((address_space(3))) void*)l, 16, 0, 0);
}

// ---------------- head: cast fp32->bf16 | Weff fold | bias concat | lsum zero ----------------
__global__ __launch_bounds__(256)
void k_head(const float* __restrict__ x, __hip_bfloat16* __restrict__ Xb,
            const float* __restrict__ W0, const float* __restrict__ A0, const float* __restrict__ B0,
            const float* __restrict__ W1, const float* __restrict__ A1, const float* __restrict__ B1,
            const float* __restrict__ W2, const float* __restrict__ A2, const float* __restrict__ B2,
            const float* __restrict__ bq, const float* __restrict__ bk, const float* __restrict__ bv,
            __hip_bfloat16* __restrict__ WeA, float* __restrict__ bcat, float* __restrict__ lsum) {
  const int b = blockIdx.x;
  if (b < 3072) {                       // ---- cast: 8192x768 fp32 -> bf16, 8/thread ----
    long i = ((long)b * 256 + threadIdx.x) * 8;
    float4 a = *(const float4*)&x[i];
    float4 c = *(const float4*)&x[i + 4];
    union { bf8 v; unsigned short h[8]; } u;
    u.h[0] = f2bf(a.x); u.h[1] = f2bf(a.y); u.h[2] = f2bf(a.z); u.h[3] = f2bf(a.w);
    u.h[4] = f2bf(c.x); u.h[5] = f2bf(c.y); u.h[6] = f2bf(c.z); u.h[7] = f2bf(c.w);
    *(bf8*)&Xb[i] = u.v;
  } else {                              // ---- fold: Weff = W + B@A, concat [2304][768] ----
    int idx = (b - 3072) * 256 + threadIdx.x;
    if (idx < 2304)
      bcat[idx] = (idx < 768) ? bq[idx] : (idx < 1536) ? bk[idx - 768] : bv[idx - 1536];
    if (idx < 8192) lsum[idx] = 0.0f;
    int t = idx / 589824, j = idx - t * 589824;
    const float* W = (t == 0) ? W0 : (t == 1) ? W1 : W2;
    const float* A = (t == 0) ? A0 : (t == 1) ? A1 : A2;
    const float* Bl = (t == 0) ? B0 : (t == 1) ? B1 : B2;
    int d = j % 768, o = j / 768;
    float acc = W[j];
    #pragma unroll
    for (int r = 0; r < 32; ++r) acc += Bl[o * 32 + r] * A[r * 768 + d];
    WeA[idx] = __float2bfloat16(acc);
  }
}

// ---------------- 128x128x64 8-wave N-marching GEMM (r8 template) ----------------
// Out[m][n] = sum_k A[m][k] * B[n][k]
// MODE 0: PV   (A=P' ld4096, B=Vt ld8192 +z*4096, fp32 out / lsum)     MARCH=1
// MODE 1: scores (A=Q ld1536, B=A+768; P'=exp2(acc*scale2) + atomic lsum) MARCH=4
// MODE 3: proj (col<1536 -> bf16 [8192][1536] +bias; else Vt +bias)     MARCH=3
template<int MODE, int MARCH>
__global__ __launch_bounds__(512, 4)
void k_gm(const __hip_bfloat16* __restrict__ Ag, const __hip_bfloat16* __restrict__ Bg,
          const float* __restrict__ bias, void* __restrict__ Og, void* __restrict__ Og2,
          float* __restrict__ lsum, float scale)
{
  __shared__ short lds[32768];   // 64 KiB: [buf2][opA/B][2half][64x64 bf16]
  constexpr int NT = (MODE == 0) ? 64 : 12;
  constexpr int S = NT * MARCH;
  const int tid = threadIdx.x, w = tid >> 6, lane = tid & 63;
  const int wm = w >> 2, wn = w & 3;
  const int lnlo = lane & 15, lnhi = lane >> 4;

  // T1 XCD swizzle, N-fast tile mapping
  const int gy = gridDim.y;
  const int nwg = gridDim.x * gy;
  const int w0 = blockIdx.y * gridDim.x + blockIdx.x;
  const int wid = (w0 & 7) * (nwg >> 3) + (w0 >> 3);
  const long M0 = (long)(wid / gy) * 128;
  const long NG0 = (long)(wid % gy) * (128 * MARCH);

  const __hip_bfloat16 *A, *B; long lda, ldb;
  if constexpr (MODE == 0) {
    A = Ag + (long)blockIdx.z * 4096 * 4096; lda = 4096;
    B = Bg + (long)blockIdx.z * 4096;        ldb = 8192;
  } else if constexpr (MODE == 1) {
    A = Ag + (long)blockIdx.z * 4096 * 1536; B = A + 768; lda = 1536; ldb = 1536;
  } else {
    A = Ag; B = Bg; lda = 768; ldb = 768;
  }

  // staging: half-tile 64 rows x 64 k = 1 gload16/thread; T2 pre-swizzled source col
  const int srow = tid >> 3;                       // 0..63
  const int scol = (((tid & 7) ^ (srow & 7)) << 3);
  const __hip_bfloat16* pA[2] = { A + (M0 + srow) * lda + scol, A + (M0 + 64 + srow) * lda + scol };
  const __hip_bfloat16* pB[2] = { B + (NG0 + srow) * ldb + scol, B + (NG0 + 64 + srow) * ldb + scol };
  char* Lc = (char*)lds;
  const int wbyte = w * 1024;
  auto stage = [&](int op, int h, int s) {         // 1 gload16/thread
    char* dst = Lc + (s & 1) * 32768 + op * 16384 + h * 8192 + wbyte;  // wave-uniform
    long off;
    if (op == 0) off = (long)(s % NT) * 64;
    else         off = (long)(s / NT) * 128 * ldb + (long)(s % NT) * 64;
    gload16((op ? pB[h] : pA[h]) + off, dst);
  };
  auto rdA = [&](int row, int k, int d) -> bf8 {   // T2-swizzled LDS read
    const int sb = ((k << 6) + (lnhi << 4)) ^ ((row & 7) << 4);
    return *(const bf8*)(Lc + d * 32768 + row * 128 + sb);
  };
  auto rdB = [&](int row, int k, int d) -> bf8 {
    const int sb = ((k << 6) + (lnhi << 4)) ^ ((row & 7) << 4);
    return *(const bf8*)(Lc + d * 32768 + 16384 + row * 128 + sb);
  };

  f32x4 acc[4][2] = {};   // wave tile 64x32: [m-frag][n-frag]

  // per-n-tile epilogue (no LDS use -> overlaps with in-flight staging)
  auto dump = [&](int j) {
    #pragma unroll
    for (int mi = 0; mi < 4; ++mi) {
      const long row = M0 + wm * 64 + mi * 16 + lnhi * 4;
      if constexpr (MODE == 0) {
        float* Of = (float*)Og + (long)blockIdx.z * 4096 * 768;
        const float* lz = lsum + (long)blockIdx.z * 4096;
        float linv[4];
        #pragma unroll
        for (int r = 0; r < 4; ++r) linv[r] = 1.0f / lz[row + r];
        #pragma unroll
        for (int ni = 0; ni < 2; ++ni) {
          const long col = NG0 + wn * 32 + ni * 16 + lnlo;
          #pragma unroll
          for (int r = 0; r < 4; ++r) Of[(row + r) * 768 + col] = acc[mi][ni][r] * linv[r];
        }
      } else if constexpr (MODE == 1) {
        __hip_bfloat16* Ob = (__hip_bfloat16*)Og + (long)blockIdx.z * 4096 * 4096;
        float* lz = lsum + (long)blockIdx.z * 4096;
        float rs[4] = {0.f, 0.f, 0.f, 0.f};
        #pragma unroll
        for (int ni = 0; ni < 2; ++ni) {
          const long col = NG0 + (long)j * 128 + wn * 32 + ni * 16 + lnlo;
          #pragma unroll
          for (int r = 0; r < 4; ++r) {
            const float e = exp2f(fminf(acc[mi][ni][r] * scale, 101.0f));  // scale has log2e folded
            rs[r] += e;
            *(unsigned short*)&Ob[(row + r) * 4096 + col] = f2bf(e);
          }
        }
        #pragma unroll
        for (int r = 0; r < 4; ++r) {
          float v = rs[r];
          v += __shfl_xor(v, 1); v += __shfl_xor(v, 2);
          v += __shfl_xor(v, 4); v += __shfl_xor(v, 8);
          if (lnlo == 0) atomicAdd(&lz[row + r], v);
        }
      } else {
        #pragma unroll
        for (int ni = 0; ni < 2; ++ni) {
          const long col = NG0 + (long)j * 128 + wn * 32 + ni * 16 + lnlo;
          const float bvl = bias[col];
          if (col < 1536) {
            __hip_bfloat16* O = (__hip_bfloat16*)Og;
            #pragma unroll
            for (int r = 0; r < 4; ++r)
              *(unsigned short*)&O[(row + r) * 1536 + col] = f2bf(acc[mi][ni][r] + bvl);
          } else {
            __hip_bfloat16* O2 = (__hip_bfloat16*)Og2;
            bf4 v;
            #pragma unroll
            for (int r = 0; r < 4; ++r) v[r] = (short)f2bf(acc[mi][ni][r] + bvl);
            *(bf4*)&O2[(col - 1536) * 8192 + row] = v;
          }
        }
      }
    }
    #pragma unroll
    for (int mi = 0; mi < 4; ++mi)
      #pragma unroll
      for (int ni = 0; ni < 2; ++ni) acc[mi][ni] = (f32x4){0.f, 0.f, 0.f, 0.f};
  };

  // prologue: B(0),A(0),B(1) -> vmcnt(2) retires tile0
  stage(1,0,0); stage(1,1,0); stage(0,0,0); stage(0,1,0);
  stage(1,0,1); stage(1,1,1);
  asm volatile("s_waitcnt vmcnt(2)" ::: "memory");
  __builtin_amdgcn_s_barrier();
  asm volatile("" ::: "memory");

  bf8 af[2][2], bv[2][2];
  for (int s = 0; s < S; s += 2) {
    if (MARCH > 1 && s > 0 && (s % NT) == 0) dump(s / NT - 1);
    const int s1 = s + 1;
    const int s2 = (s + 2 < S) ? s + 2 : S - 1;   // clamp: rewrites identical bytes
    const int s3 = (s + 3 < S) ? s + 3 : S - 1;

    // ---- P0 (buf0, m-half 0) ----
    #pragma unroll
    for (int m = 0; m < 2; ++m)
      #pragma unroll
      for (int k = 0; k < 2; ++k) af[m][k] = rdA(wm * 64 + m * 16 + lnlo, k, 0);
    #pragma unroll
    for (int n = 0; n < 2; ++n)
      #pragma unroll
      for (int k = 0; k < 2; ++k) bv[n][k] = rdB(wn * 32 + n * 16 + lnlo, k, 0);
    stage(0,0,s1); stage(0,1,s1);
    asm volatile("" ::: "memory");
    __builtin_amdgcn_s_barrier();
    __builtin_amdgcn_s_setprio(1);
    #pragma unroll
    for (int m = 0; m < 2; ++m)
      #pragma unroll
      for (int n = 0; n < 2; ++n) {
        acc[m][n] = __builtin_amdgcn_mfma_f32_16x16x32_bf16(af[m][0], bv[n][0], acc[m][n], 0,0,0);
        acc[m][n] = __builtin_amdgcn_mfma_f32_16x16x32_bf16(af[m][1], bv[n][1], acc[m][n], 0,0,0);
      }
    __builtin_amdgcn_s_setprio(0);
    __builtin_amdgcn_s_barrier();
    asm volatile("" ::: "memory");

    // ---- P1 (buf0, m-half 1) ----
    #pragma unroll
    for (int m = 0; m < 2; ++m)
      #pragma unroll
      for (int k = 0; k < 2; ++k) af[m][k] = rdA(wm * 64 + 32 + m * 16 + lnlo, k, 0);
    stage(1,0,s2); stage(1,1,s2);
    asm volatile("" ::: "memory");
    __builtin_amdgcn_s_barrier();
    __builtin_amdgcn_s_setprio(1);
    #pragma unroll
    for (int m = 0; m < 2; ++m)
      #pragma unroll
      for (int n = 0; n < 2; ++n) {
        acc[2+m][n] = __builtin_amdgcn_mfma_f32_16x16x32_bf16(af[m][0], bv[n][0], acc[2+m][n], 0,0,0);
        acc[2+m][n] = __builtin_amdgcn_mfma_f32_16x16x32_bf16(af[m][1], bv[n][1], acc[2+m][n], 0,0,0);
      }
    __builtin_amdgcn_s_setprio(0);
    asm volatile("s_waitcnt vmcnt(2)" ::: "memory");   // A(s+1),B(s+1) landed
    __builtin_amdgcn_s_barrier();
    asm volatile("" ::: "memory");

    // ---- P2 (buf1, m-half 0) ----
    #pragma unroll
    for (int m = 0; m < 2; ++m)
      #pragma unroll
      for (int k = 0; k < 2; ++k) af[m][k] = rdA(wm * 64 + m * 16 + lnlo, k, 1);
    #pragma unroll
    for (int n = 0; n < 2; ++n)
      #pragma unroll
      for (int k = 0; k < 2; ++k) bv[n][k] = rdB(wn * 32 + n * 16 + lnlo, k, 1);
    stage(0,0,s2); stage(0,1,s2);
    asm volatile("" ::: "memory");
    __builtin_amdgcn_s_barrier();
    __builtin_amdgcn_s_setprio(1);
    #pragma unroll
    for (int m = 0; m < 2; ++m)
      #pragma unroll
      for (int n = 0; n < 2; ++n) {
        acc[m][n] = __builtin_amdgcn_mfma_f32_16x16x32_bf16(af[m][0], bv[n][0], acc[m][n], 0,0,0);
        acc[m][n] = __builtin_amdgcn_mfma_f32_16x16x32_bf16(af[m][1], bv[n][1], acc[m][n], 0,0,0);
      }
    __builtin_amdgcn_s_setprio(0);
    __builtin_amdgcn_s_barrier();
    asm volatile("" ::: "memory");

    // ---- P3 (buf1, m-half 1) ----
    #pragma unroll
    for (int m = 0; m < 2; ++m)
      #pragma unroll
      for (int k = 0; k < 2; ++k) af[m][k] = rdA(wm * 64 + 32 + m * 16 + lnlo, k, 1);
    stage(1,0,s3); stage(1,1,s3);
    asm volatile("" ::: "memory");
    __builtin_amdgcn_s_barrier();
    __builtin_amdgcn_s_setprio(1);
    #pragma unroll
    for (int m = 0; m < 2; ++m)
      #pragma unroll
      for (int n = 0; n < 2; ++n) {
        acc[2+m][n] = __builtin_amdgcn_mfma_f32_16x16x32_bf16(af[m][0], bv[n][0], acc[2+m][n], 0,0,0);
        acc[2+m][n] = __builtin_amdgcn_mfma_f32_16x16x32_bf16(af[m][1], bv[n][1], acc[2+m][n], 0,0,0);
      }
    __builtin_amdgcn_s_setprio(0);
    asm volatile("s_waitcnt vmcnt(2)" ::: "memory");   // A(s+2),B(s+2) landed
    __builtin_amdgcn_s_barrier();
    asm volatile("" ::: "memory");
  }

  dump(MARCH - 1);
}

extern "C" void kernel_launch(void* const* d_in, const int* in_sizes, int n_in,
                              void* d_out, int out_size, void* d_ws, size_t ws_size,
                              hipStream_t stream) {
  const float* x  = (const float*)d_in[0];
  const float* Wq = (const float*)d_in[1]; const float* bq = (const float*)d_in[2];
  const float* Wk = (const float*)d_in[3]; const float* bk = (const float*)d_in[4];
  const float* Wv = (const float*)d_in[5]; const float* bv = (const float*)d_in[6];
  const float* Aq = (const float*)d_in[7]; const float* Bq = (const float*)d_in[8];
  const float* Ak = (const float*)d_in[9]; const float* Bk = (const float*)d_in[10];
  const float* Av = (const float*)d_in[11]; const float* Bv = (const float*)d_in[12];

  // ws layout (bf16 elems), ~121 MB
  __hip_bfloat16* Xb   = (__hip_bfloat16*)d_ws;        // [8192][768]
  __hip_bfloat16* WeA  = Xb  + 6291456;                // [2304][768]
  __hip_bfloat16* QKb  = WeA + 1769472;                // [8192][1536] (Q 0-767, K 768-1535)
  __hip_bfloat16* Vt   = QKb + 12582912;               // [768][8192]
  __hip_bfloat16* Pb   = Vt  + 6291456;                // [2][4096][4096] unnormalized exp
  float*          bcat = (float*)(Pb + 33554432);      // [2304]
  float*          lsum = bcat + 2304;                  // [2][4096] row sums
  float* out = (float*)d_out;

  // head: cast (blocks 0-3071) + fold/bias/lsum-zero (blocks 3072-9983)
  k_head<<<9984, 256, 0, stream>>>(x, Xb, Wq, Aq, Bq, Wk, Ak, Bk, Wv, Av, Bv,
                                   bq, bk, bv, WeA, bcat, lsum);

  // projections: M=8192, N=2304, K=768 (march 3 -> 384 blocks, single round)
  k_gm<3, 3><<<dim3(64, 6, 1), 512, 0, stream>>>(Xb, WeA, bcat, QKb, Vt, nullptr, 1.0f);
  // scores + exp + rowsum: per batch M=N=4096, K=768 (march 4); scale·log2e folded
  const float sc2 = 0.036084391824351615f * 1.4426950408889634f;
  k_gm<1, 4><<<dim3(32, 8, 2), 512, 0, stream>>>(QKb, nullptr, nullptr, Pb, nullptr, lsum, sc2);
  // PV: per batch M=4096, N=768, K=4096 (march 1); epilogue normalizes by lsum
  k_gm<0, 1><<<dim3(32, 6, 2), 512, 0, stream>>>(Pb, Vt, nullptr, out, nullptr, lsum, 1.0f);
}